// Round 8
// baseline (535.764 us; speedup 1.0000x reference)
//
#include <hip/hip_runtime.h>
#include <cstddef>

typedef float f32x4 __attribute__((ext_vector_type(4)));
typedef float f32x16 __attribute__((ext_vector_type(16)));
typedef __bf16 bf16x8 __attribute__((ext_vector_type(8)));
typedef unsigned short u16x8 __attribute__((ext_vector_type(8)));
typedef unsigned short u16x4 __attribute__((ext_vector_type(4)));

constexpr int NB = 2, S = 4096, H = 16, D = 128;
constexpr int DIN = 2048, NQKV = 6144, HD = 2048;
constexpr int BLK = 256, NBL = 16;

constexpr size_t SZ_XB    = (size_t)NB * S * DIN * 2;
constexpr size_t SZ_WQKVT = (size_t)NQKV * DIN * 2;
constexpr size_t SZ_WGT   = (size_t)HD * DIN * 2;
constexpr size_t SZ_WOUTT = (size_t)HD * HD * 2;
constexpr size_t SZ_QKVB  = (size_t)NB * S * NQKV * 2;
constexpr size_t SZ_GB    = (size_t)NB * S * HD * 2;
constexpr size_t SZ_ST    = (size_t)NB * H * NBL * D * D * 2;
constexpr size_t SZ_OB    = (size_t)NB * S * HD * 2;

__device__ __forceinline__ float bf2f(unsigned short u) {
  return __uint_as_float(((unsigned)u) << 16);
}
__device__ __forceinline__ unsigned short f2bf(float f) {
  unsigned u = __float_as_uint(f);
  u += 0x7fffu + ((u >> 16) & 1u);
  return (unsigned short)(u >> 16);
}
__device__ __forceinline__ void gload16(const void* g, void* l) {
  __builtin_amdgcn_global_load_lds(
      (const __attribute__((address_space(1))) unsigned int*)g,
      (__attribute__((address_space(3))) unsigned int*)l, 16, 0, 0);
}

// ---------------- fp32 -> bf16 elementwise convert (8 elems/thread) --------
__global__ __launch_bounds__(256) void cvt_bf16(
    const float* __restrict__ in, unsigned short* __restrict__ out) {
  const size_t id = (size_t)blockIdx.x * 256 + threadIdx.x;
  const float4 a = *(const float4*)&in[id * 8];
  const float4 c = *(const float4*)&in[id * 8 + 4];
  u16x8 o;
  o[0] = f2bf(a.x); o[1] = f2bf(a.y); o[2] = f2bf(a.z); o[3] = f2bf(a.w);
  o[4] = f2bf(c.x); o[5] = f2bf(c.y); o[6] = f2bf(c.z); o[7] = f2bf(c.w);
  *(u16x8*)&out[id * 8] = o;
}

// ---------------- W[K][N] f32  ->  Wt[N][K] bf16 (32x32 LDS tiles) ---------
__global__ __launch_bounds__(256) void transpose_cvt(
    const float* __restrict__ W, unsigned short* __restrict__ Wt, int K, int N) {
  __shared__ unsigned short tile[32][33];
  const int n0 = blockIdx.x * 32, k0 = blockIdx.y * 32;
  const int t = threadIdx.x;
  const int r = t >> 3, c4 = (t & 7) * 4;
  const float4 v = *(const float4*)&W[(size_t)(k0 + r) * N + n0 + c4];
  tile[r][c4 + 0] = f2bf(v.x);
  tile[r][c4 + 1] = f2bf(v.y);
  tile[r][c4 + 2] = f2bf(v.z);
  tile[r][c4 + 3] = f2bf(v.w);
  __syncthreads();
  u16x4 o;
  #pragma unroll
  for (int i = 0; i < 4; ++i) o[i] = tile[c4 + i][r];
  *(u16x4*)&Wt[(size_t)(n0 + r) * K + k0 + c4] = o;
}

// ---------------- 128^2 m97-structure bf16 MFMA GEMM (32x32x16 shape) ------
// A [M][K], Bt [N][K] bf16 row-major. 256 thr = 4 waves (2Mx2N), 64x64/wave
// as 2x2 of 32x32 MFMA frags. BK=64, SINGLE 32 KiB LDS buffer, 2-barrier
// loop + vmcnt(0) drain; 4 blocks/CU (launch_bounds(256,4)) cover the drain.
// Swizzle: 16B slot = cg ^ (row&7), cg = 2*kk + (lane>>5); linear LDS dst
// t*16, pre-swizzled global source cg=(t&7)^((t>>3)&7).
// 32x32 C/D: col=lane&31, row=(reg&3)+8*(reg>>2)+4*(lane>>5) [m74/m101].
// ACT: 0 -> f32 into O1 (stride N); 3 -> fused split: gc<NSPLIT silu->O1
// bf16 (stride NSPLIT), else sigmoid->O2 bf16 (stride N-NSPLIT).
template<int ACT>
__global__ __launch_bounds__(256, 4) void gemm128(
    const unsigned short* __restrict__ A, const unsigned short* __restrict__ Bt,
    void* __restrict__ O1, void* __restrict__ O2,
    int M, int N, int K, int NSPLIT) {
  __shared__ unsigned short lds[16384];          // 32 KiB: A 16K + B 16K
  char* ldsb = (char*)lds;
  const int t = threadIdx.x;
  const int lane = t & 63, wave = t >> 6;
  const int wr = wave >> 1, wc = wave & 1;
  const int l31 = lane & 31;

  const int nbm = M >> 7;
  const int nbmx = nbm >> 3;
  const int xcd = blockIdx.x & 7, q = blockIdx.x >> 3;
  const int bm = xcd * nbmx + (q % nbmx);
  const int bn = q / nbmx;

  const int cg = (t & 7) ^ ((t >> 3) & 7);
  const unsigned short* sA = A  + (size_t)(bm * 128 + (t >> 3)) * K + cg * 8;
  const unsigned short* sB = Bt + (size_t)(bn * 128 + (t >> 3)) * K + cg * 8;
  const int dstb = t << 4;

  // ds_read byte offsets: row*128 + ((2*kk + lane>>5) ^ (row&7))*16
  int offA[4][2], offB[4][2];
  #pragma unroll
  for (int kk = 0; kk < 4; ++kk) {
    const int cgk = 2 * kk + (lane >> 5);
    #pragma unroll
    for (int m = 0; m < 2; ++m) {
      const int row = wr * 64 + m * 32 + l31;
      offA[kk][m] = row * 128 + ((cgk ^ (row & 7)) << 4);
    }
    #pragma unroll
    for (int n = 0; n < 2; ++n) {
      const int row = wc * 64 + n * 32 + l31;
      offB[kk][n] = 16384 + row * 128 + ((cgk ^ (row & 7)) << 4);
    }
  }

  const int NT = K >> 6;
  f32x16 acc[2][2] = {};
  for (int u = 0; u < NT; ++u) {
    __syncthreads();
    const int ko = u * 64;
    #pragma unroll
    for (int i = 0; i < 4; ++i) {
      gload16(sA + (size_t)(i * 32) * K + ko, ldsb + i * 4096 + dstb);
      gload16(sB + (size_t)(i * 32) * K + ko, ldsb + 16384 + i * 4096 + dstb);
    }
    asm volatile("s_waitcnt vmcnt(0)" ::: "memory");
    __syncthreads();
    #pragma unroll
    for (int kk = 0; kk < 4; ++kk) {
      bf16x8 af[2], bfr[2];
      #pragma unroll
      for (int m = 0; m < 2; ++m) af[m] = *(const bf16x8*)(ldsb + offA[kk][m]);
      #pragma unroll
      for (int n = 0; n < 2; ++n) bfr[n] = *(const bf16x8*)(ldsb + offB[kk][n]);
      #pragma unroll
      for (int m = 0; m < 2; ++m)
        #pragma unroll
        for (int n = 0; n < 2; ++n)
          acc[m][n] = __builtin_amdgcn_mfma_f32_32x32x16_bf16(af[m], bfr[n], acc[m][n], 0, 0, 0);
    }
  }

  // epilogue: 32x32 C/D layout col=lane&31, row=(reg&3)+8*(reg>>2)+4*(lane>>5)
  const int rbase = 4 * (lane >> 5);
  const bool lo = (bn * 128) < NSPLIT;
  #pragma unroll
  for (int m = 0; m < 2; ++m)
    #pragma unroll
    for (int n = 0; n < 2; ++n) {
      const int gc = bn * 128 + wc * 64 + n * 32 + l31;
      #pragma unroll
      for (int reg = 0; reg < 16; ++reg) {
        const int gr = bm * 128 + wr * 64 + m * 32 + rbase + (reg & 3) + 8 * (reg >> 2);
        float v = acc[m][n][reg];
        if constexpr (ACT == 0) {
          ((float*)O1)[(size_t)gr * N + gc] = v;
        } else {
          if (lo) {
            v = v / (1.f + __expf(-v));          // silu
            ((unsigned short*)O1)[(size_t)gr * NSPLIT + gc] = f2bf(v);
          } else {
            v = 1.f / (1.f + __expf(-v));        // sigmoid
            ((unsigned short*)O2)[(size_t)gr * (N - NSPLIT) + (gc - NSPLIT)] = f2bf(v);
          }
        }
      }
    }
}

// ---------------- per-block KV outer product (MFMA), TRANSPOSED out --------
// st[(bh*NBL+j)][f][e] = sum_m (k[m][e]*kdecay[m]) * v[m][f]   (bf16)
__global__ __launch_bounds__(256) void kv_outer(
    const unsigned short* __restrict__ qkv, unsigned short* __restrict__ st) {
  const int gid = blockIdx.x;
  const int j = gid & 15;
  const int bh = gid >> 4;
  const int h = bh & 15;
  const int b = bh >> 4;
  const float slope = exp2f(-0.5f * (float)(h + 1));
  const int t = threadIdx.x;
  const int lane = t & 63, wave = t >> 6, wr = wave >> 1, wc = wave & 1;
  const int l15 = lane & 15;
  __shared__ unsigned short vt[128][72];   // vT [f][mm]
  __shared__ unsigned short kt[128][72];   // (k*kd)T [e][mm]
  f32x4 acc[4][4] = {};
  const int mm = t & 63;                   // m within chunk
  const int c0 = (t >> 6) * 32;            // 32-col span per wave
  for (int ch = 0; ch < 4; ++ch) {
    if (ch) __syncthreads();
    const int m = ch * 64 + mm;
    const int seq = b * S + j * BLK + m;
    const float kd = expf(-slope * (float)(255 - m));
    const unsigned short* row = &qkv[(size_t)seq * NQKV + h * 384];
    #pragma unroll
    for (int i = 0; i < 4; ++i) {
      const u16x8 k8 = *(const u16x8*)&row[128 + c0 + i * 8];
      const u16x8 v8 = *(const u16x8*)&row[256 + c0 + i * 8];
      #pragma unroll
      for (int q2 = 0; q2 < 8; ++q2) {
        kt[c0 + i * 8 + q2][mm] = f2bf(bf2f(k8[q2]) * kd);
        vt[c0 + i * 8 + q2][mm] = v8[q2];
      }
    }
    __syncthreads();
    #pragma unroll
    for (int kk = 0; kk < 2; ++kk) {
      bf16x8 af[4], bfr[4];
      #pragma unroll
      for (int mi = 0; mi < 4; ++mi)
        af[mi] = *(const bf16x8*)&vt[wr * 64 + mi * 16 + l15][kk * 32 + (lane >> 4) * 8];
      #pragma unroll
      for (int n = 0; n < 4; ++n)
        bfr[n] = *(const bf16x8*)&kt[wc * 64 + n * 16 + l15][kk * 32 + (lane >> 4) * 8];
      #pragma unroll
      for (int mi = 0; mi < 4; ++mi)
        #pragma unroll
        for (int n = 0; n < 4; ++n)
          acc[mi][n] = __builtin_amdgcn_mfma_f32_16x16x32_bf16(af[mi], bfr[n], acc[mi][n], 0, 0, 0);
    }
  }
  const size_t base = (size_t)gid * (D * D);
  const int ro = (lane >> 4) * 4;
  #pragma unroll
  for (int mi = 0; mi < 4; ++mi)
    #pragma unroll
    for (int n = 0; n < 4; ++n) {
      const int e = wc * 64 + n * 16 + l15;
      #pragma unroll
      for (int r = 0; r < 4; ++r) {
        const int f = wr * 64 + mi * 16 + ro + r;
        st[base + (size_t)f * D + e] = f2bf(acc[mi][n][r]);
      }
    }
}

// ---------------- exclusive decay scan over blocks (per element) -----------
__global__ __launch_bounds__(256) void kv_scan(unsigned short* __restrict__ st) {
  const int id = blockIdx.x * 256 + threadIdx.x;  // NB*H*D*D threads
  const int ef = id & (D * D - 1);
  const int bh = id >> 14;
  const int h = bh & 15;
  const float slope = exp2f(-0.5f * (float)(h + 1));
  const float bd = expf(-slope * 256.f);
  unsigned short* p = st + (size_t)bh * NBL * D * D + ef;
  float cur = 0.f;
  #pragma unroll
  for (int jj = 0; jj < NBL; ++jj) {
    const float m = bf2f(p[(size_t)jj * D * D]);
    p[(size_t)jj * D * D] = f2bf(cur);
    cur = bd * cur + m;
  }
}

// ---------------- MFMA attention (q in registers, 2 blocks/CU) -------------
// grid = ((b*H+h)*NBL + j)*2 + half ; WG = 4 waves, 128 q-rows x 128 dims.
// out = qdecay.*(q @ kvT^T) + (mask(q@k^T).*decay) @ v
__global__ __launch_bounds__(256, 2) void attn_mfma(
    const unsigned short* __restrict__ qkv, const unsigned short* __restrict__ st,
    unsigned short* __restrict__ ob) {
  const int gid = blockIdx.x;
  const int half = gid & 1;
  const int rest = gid >> 1;
  const int j = rest & 15;
  const int bh = rest >> 4;
  const int h = bh & 15;
  const int b = bh >> 4;
  const float slope = exp2f(-0.5f * (float)(h + 1));
  const int t = threadIdx.x;
  const int lane = t & 63, wave = t >> 6, wr = wave >> 1, wc = wave & 1;

  __shared__ unsigned short cb[128][136];   // kvT / k / vT chunk buffer
  __shared__ unsigned short pl[128][136];   // decayed P (m x m') bf16

  // q fragments direct from global (L2-resident; frag layout = MFMA A-frag)
  bf16x8 af[4][4];                          // [kk][m]
  #pragma unroll
  for (int m = 0; m < 4; ++m) {
    const int seq = b * S + j * BLK + half * 128 + wr * 64 + m * 16 + (lane & 15);
    const unsigned short* qrow = &qkv[(size_t)seq * NQKV + h * 384];
    #pragma unroll
    for (int kk = 0; kk < 4; ++kk)
      af[kk][m] = *(const bf16x8*)&qrow[kk * 32 + (lane >> 4) * 8];
  }
  // stage kvT (state pre-transposed [f][e], exclusive-scanned)
  {
    const int r = t >> 4, c0 = (t & 15) * 8;
    const size_t stbase = (size_t)rest * (D * D);
    #pragma unroll
    for (int p = 0; p < 8; ++p)
      *(u16x8*)&cb[r + p * 16][c0] = *(const u16x8*)&st[stbase + (size_t)(r + p * 16) * D + c0];
  }
  __syncthreads();

  f32x4 acc[4][4] = {};
  // ---- phase 1: non-diag = q @ kvT^T ----
  #pragma unroll
  for (int kk = 0; kk < 4; ++kk) {
    bf16x8 bfr[4];
    #pragma unroll
    for (int n = 0; n < 4; ++n)
      bfr[n] = *(const bf16x8*)&cb[wc * 64 + n * 16 + (lane & 15)][kk * 32 + (lane >> 4) * 8];
    #pragma unroll
    for (int m = 0; m < 4; ++m)
      #pragma unroll
      for (int n = 0; n < 4; ++n)
        acc[m][n] = __builtin_amdgcn_mfma_f32_16x16x32_bf16(af[kk][m], bfr[n], acc[m][n], 0, 0, 0);
  }
  // apply q_decay = exp(-slope*(gm+1))
  const int ro = (lane >> 4) * 4;
  #pragma unroll
  for (int m = 0; m < 4; ++m)
    #pragma unroll
    for (int r = 0; r < 4; ++r) {
      const int gm = half * 128 + wr * 64 + m * 16 + ro + r;
      const float qd = expf(-slope * (float)(gm + 1));
      #pragma unroll
      for (int n = 0; n < 4; ++n) acc[m][n][r] *= qd;
    }

  // ---- phase 2: intra-block causal, chunks of 128 k-rows ----
  const int nch = 1 + half;
  for (int c = 0; c < nch; ++c) {
    __syncthreads();                         // cb readers retired
    {
      const int r = t >> 4, c0 = (t & 15) * 8;
      #pragma unroll
      for (int p = 0; p < 8; ++p) {
        const int seq = b * S + j * BLK + c * 128 + r + p * 16;
        *(u16x8*)&cb[r + p * 16][c0] = *(const u16x8*)&qkv[(size_t)seq * NQKV + h * 384 + 128 + c0];
      }
    }
    __syncthreads();
    f32x4 sacc[4][4] = {};
    #pragma unroll
    for (int kk = 0; kk < 4; ++kk) {
      bf16x8 bfr[4];
      #pragma unroll
      for (int n = 0; n < 4; ++n)
        bfr[n] = *(const bf16x8*)&cb[wc * 64 + n * 16 + (lane & 15)][kk * 32 + (lane >> 4) * 8];
      #pragma unroll
      for (int m = 0; m < 4; ++m)
        #pragma unroll
        for (int n = 0; n < 4; ++n)
          sacc[m][n] = __builtin_amdgcn_mfma_f32_16x16x32_bf16(af[kk][m], bfr[n], sacc[m][n], 0, 0, 0);
    }
    // decay+mask -> P (bf16) in LDS
    #pragma unroll
    for (int m = 0; m < 4; ++m)
      #pragma unroll
      for (int n = 0; n < 4; ++n) {
        const int lc = wc * 64 + n * 16 + (lane & 15);
        const int gp = c * 128 + lc;
        #pragma unroll
        for (int r = 0; r < 4; ++r) {
          const int lm = wr * 64 + m * 16 + ro + r;
          const int gm = half * 128 + lm;
          const float dd = (gm >= gp) ? expf(-slope * (float)(gm - gp)) : 0.f;
          pl[lm][lc] = f2bf(sacc[m][n][r] * dd);
        }
      }
    __syncthreads();                         // P complete; cb(k) readers done
    // stage v transposed: cb[f][m']
    {
      const int vr = t & 15, vc0 = (t >> 4) * 8;
      #pragma unroll
      for (int p = 0; p < 8; ++p) {
        const int row = vr + p * 16;
        const int seq = b * S + j * BLK + c * 128 + row;
        const u16x8 vv = *(const u16x8*)&qkv[(size_t)seq * NQKV + h * 384 + 256 + vc0];
        #pragma unroll
        for (int i = 0; i < 8; ++i) cb[vc0 + i][row] = vv[i];
      }
    }
    __syncthreads();
    // PV: acc += P @ vT^T
    #pragma unroll
    for (int kk = 0; kk < 4; ++kk) {
      bf16x8 pf[4], bfr[4];
      #pragma unroll
      for (int m = 0; m < 4; ++m)
        pf[m] = *(const bf16x8*)&pl[wr * 64 + m * 16 + (lane & 15)][kk * 32 + (lane >> 4) * 8];
      #pragma unroll
      for (int n = 0; n < 4; ++n)
        bfr[n] = *(const bf16x8*)&cb[wc * 64 + n * 16 + (lane & 15)][kk * 32 + (lane >> 4) * 8];
      #pragma unroll
      for (int m = 0; m < 4; ++m)
        #pragma unroll
        for (int n = 0; n < 4; ++n)
          acc[m][n] = __builtin_amdgcn_mfma_f32_16x16x32_bf16(pf[m], bfr[n], acc[m][n], 0, 0, 0);
    }
  }

  // epilogue: ob[b][n][h*D + f]
  #pragma unroll
  for (int m = 0; m < 4; ++m)
    #pragma unroll
    for (int n = 0; n < 4; ++n) {
      const int fc = h * D + wc * 64 + n * 16 + (lane & 15);
      #pragma unroll
      for (int r = 0; r < 4; ++r) {
        const int seq = b * S + j * BLK + half * 128 + wr * 64 + m * 16 + ro + r;
        ob[(size_t)seq * HD + fc] = f2bf(acc[m][n][r]);
      }
    }
}

// ---------------- RMSNorm * norm_w * sigmoid-gate -> bf16 ------------------
__global__ __launch_bounds__(256) void norm_gate(
    const unsigned short* __restrict__ ob, const unsigned short* __restrict__ gb,
    const float* __restrict__ nw, unsigned short* __restrict__ og) {
  const int row = blockIdx.x;
  const int t = threadIdx.x;
  const u16x8 ov = *(const u16x8*)&ob[(size_t)row * HD + t * 8];
  float f[8];
  float ss = 0.f;
  #pragma unroll
  for (int i = 0; i < 8; ++i) { f[i] = bf2f(ov[i]); ss += f[i] * f[i]; }
  #pragma unroll
  for (int off = 32; off > 0; off >>= 1) ss += __shfl_down(ss, off, 64);
  __shared__ float red[4];
  if ((t & 63) == 0) red[t >> 6] = ss;
  __syncthreads();
  const float rms = rsqrtf((red[0] + red[1] + red[2] + red[3]) * (1.f / HD) + 1e-6f);
  const u16x8 gv = *(const u16x8*)&gb[(size_t)row * HD + t * 8];
  u16x8 ow;
  #pragma unroll
  for (int i = 0; i < 8; ++i)
    ow[i] = f2bf(f[i] * rms * nw[t * 8 + i] * bf2f(gv[i]));
  *(u16x8*)&og[(size_t)row * HD + t * 8] = ow;
}

extern "C" void kernel_launch(void* const* d_in, const int* in_sizes, int n_in,
                              void* d_out, int out_size, void* d_ws, size_t ws_size,
                              hipStream_t stream) {
  (void)in_sizes; (void)n_in; (void)out_size; (void)ws_size;
  const float* x    = (const float*)d_in[0];
  const float* Wqkv = (const float*)d_in[1];
  const float* Wg   = (const float*)d_in[2];
  const float* Wout = (const float*)d_in[3];
  const float* nw   = (const float*)d_in[4];

  char* ws = (char*)d_ws;
  unsigned short* xb    = (unsigned short*)ws; ws += SZ_XB;
  unsigned short* wqkvt = (unsigned short*)ws; ws += SZ_WQKVT;  // [6144][2048]
  unsigned short* wgt   = (unsigned short*)ws; ws += SZ_WGT;    // [2048][2048] (contiguous after wqkvt)
  unsigned short* woutt = (unsigned short*)ws; ws += SZ_WOUTT;
  unsigned short* qkvb  = (unsigned short*)ws; ws += SZ_QKVB;
  unsigned short* gb    = (unsigned short*)ws; ws += SZ_GB;
  unsigned short* st    = (unsigned short*)ws; ws += SZ_ST;
  unsigned short* ob    = (unsigned short*)ws; ws += SZ_OB;
  unsigned short* og    = xb;  // alias: xb dead after the fused GEMM
  (void)wgt;

  cvt_bf16<<<dim3((NB * S * DIN) / (256 * 8)), 256, 0, stream>>>(x, xb);
  transpose_cvt<<<dim3(NQKV / 32, DIN / 32), 256, 0, stream>>>(Wqkv, wqkvt, DIN, NQKV);
  transpose_cvt<<<dim3(HD / 32, DIN / 32), 256, 0, stream>>>(Wg, wgt, DIN, HD);
  transpose_cvt<<<dim3(HD / 32, HD / 32), 256, 0, stream>>>(Wout, woutt, HD, HD);

  // fused: [qkv | gate] = x @ [Wqkv | Wg]; N = 8192, split at 6144
  gemm128<3><<<dim3((NB * S / 128) * ((NQKV + HD) / 128)), 256, 0, stream>>>(
      xb, wqkvt, qkvb, gb, NB * S, NQKV + HD, DIN, NQKV);

  kv_outer<<<dim3(NB * H * NBL), 256, 0, stream>>>(qkvb, st);
  kv_scan<<<dim3((NB * H * D * D) / 256), 256, 0, stream>>>(st);
  attn_mfma<<<dim3(NB * H * NBL * 2), 256, 0, stream>>>(qkvb, st, ob);

  norm_gate<<<dim3(NB * S), 256, 0, stream>>>(ob, gb, nw, og);
  gemm128<0><<<dim3((NB * S / 128) * (HD / 128)), 256, 0, stream>>>(
      og, woutt, d_out, nullptr, NB * S, HD, HD, 0);
}

// Round 9
// 478.772 us; speedup vs baseline: 1.1190x; 1.1190x over previous
//
#include <hip/hip_runtime.h>
#include <cstddef>

typedef float f32x4 __attribute__((ext_vector_type(4)));
typedef __bf16 bf16x8 __attribute__((ext_vector_type(8)));
typedef unsigned short u16x8 __attribute__((ext_vector_type(8)));
typedef unsigned short u16x4 __attribute__((ext_vector_type(4)));

constexpr int NB = 2, S = 4096, H = 16, D = 128;
constexpr int DIN = 2048, NQKV = 6144, HD = 2048;
constexpr int BLK = 256, NBL = 16;

constexpr size_t SZ_XB    = (size_t)NB * S * DIN * 2;
constexpr size_t SZ_WQKVT = (size_t)NQKV * DIN * 2;
constexpr size_t SZ_WGT   = (size_t)HD * DIN * 2;
constexpr size_t SZ_WOUTT = (size_t)HD * HD * 2;
constexpr size_t SZ_QKVB  = (size_t)NB * S * NQKV * 2;
constexpr size_t SZ_GB    = (size_t)NB * S * HD * 2;
constexpr size_t SZ_ST    = (size_t)NB * H * NBL * D * D * 2;
constexpr size_t SZ_OB    = (size_t)NB * S * HD * 2;

__device__ __forceinline__ float bf2f(unsigned short u) {
  return __uint_as_float(((unsigned)u) << 16);
}
__device__ __forceinline__ unsigned short f2bf(float f) {
  unsigned u = __float_as_uint(f);
  u += 0x7fffu + ((u >> 16) & 1u);
  return (unsigned short)(u >> 16);
}
__device__ __forceinline__ void gload16(const void* g, void* l) {
  __builtin_amdgcn_global_load_lds(
      (const __attribute__((address_space(1))) unsigned int*)g,
      (__attribute__((address_space(3))) unsigned int*)l, 16, 0, 0);
}

// ---------------- fp32 -> bf16 elementwise convert (8 elems/thread) --------
__global__ __launch_bounds__(256) void cvt_bf16(
    const float* __restrict__ in, unsigned short* __restrict__ out) {
  const size_t id = (size_t)blockIdx.x * 256 + threadIdx.x;
  const float4 a = *(const float4*)&in[id * 8];
  const float4 c = *(const float4*)&in[id * 8 + 4];
  u16x8 o;
  o[0] = f2bf(a.x); o[1] = f2bf(a.y); o[2] = f2bf(a.z); o[3] = f2bf(a.w);
  o[4] = f2bf(c.x); o[5] = f2bf(c.y); o[6] = f2bf(c.z); o[7] = f2bf(c.w);
  *(u16x8*)&out[id * 8] = o;
}

// ---------------- W[K][N] f32  ->  Wt[N][K] bf16 (32x32 LDS tiles) ---------
__global__ __launch_bounds__(256) void transpose_cvt(
    const float* __restrict__ W, unsigned short* __restrict__ Wt, int K, int N) {
  __shared__ unsigned short tile[32][33];
  const int n0 = blockIdx.x * 32, k0 = blockIdx.y * 32;
  const int t = threadIdx.x;
  const int r = t >> 3, c4 = (t & 7) * 4;
  const float4 v = *(const float4*)&W[(size_t)(k0 + r) * N + n0 + c4];
  tile[r][c4 + 0] = f2bf(v.x);
  tile[r][c4 + 1] = f2bf(v.y);
  tile[r][c4 + 2] = f2bf(v.z);
  tile[r][c4 + 3] = f2bf(v.w);
  __syncthreads();
  u16x4 o;
  #pragma unroll
  for (int i = 0; i < 4; ++i) o[i] = tile[c4 + i][r];
  *(u16x4*)&Wt[(size_t)(n0 + r) * K + k0 + c4] = o;
}

// ---------------- 128^2 m97-structure bf16 MFMA GEMM (16x16x32) ------------
// A [M][K], Bt [N][K] bf16 row-major. 256 thr = 4 waves (2Mx2N), 64x64/wave.
// BK=64, SINGLE 32 KiB LDS buffer, 2-barrier loop + vmcnt(0) drain; 4
// blocks/CU (launch_bounds(256,4); 32KB LDS allows 5) give cross-block
// overlap that covers the drain stall (m114/m97). Swizzle: 16B slot =
// colgrp ^ (row&7); linear LDS dst t*16, pre-swizzled global source.
// NOTE (R8 lesson): 32x32 frags here are a structural 4-way LDS conflict
// (32 lanes x 1 cg over 8 slots) -- 16x16 is the conflict-free shape.
// ACT: 0 -> f32 into O1 (stride N); 3 -> fused split: gc<NSPLIT silu->O1
// bf16 (stride NSPLIT), else sigmoid->O2 bf16 (stride N-NSPLIT).
template<int ACT>
__global__ __launch_bounds__(256, 4) void gemm128(
    const unsigned short* __restrict__ A, const unsigned short* __restrict__ Bt,
    void* __restrict__ O1, void* __restrict__ O2,
    int M, int N, int K, int NSPLIT) {
  __shared__ unsigned short lds[16384];          // 32 KiB: A 16K + B 16K
  char* ldsb = (char*)lds;
  const int t = threadIdx.x;
  const int lane = t & 63, wave = t >> 6;
  const int wr = wave >> 1, wc = wave & 1;
  const int l15 = lane & 15;

  const int nbm = M >> 7;
  const int nbmx = nbm >> 3;
  const int xcd = blockIdx.x & 7, q = blockIdx.x >> 3;
  const int bm = xcd * nbmx + (q % nbmx);
  const int bn = q / nbmx;

  const int cg = (t & 7) ^ ((t >> 3) & 7);
  const unsigned short* sA = A  + (size_t)(bm * 128 + (t >> 3)) * K + cg * 8;
  const unsigned short* sB = Bt + (size_t)(bn * 128 + (t >> 3)) * K + cg * 8;
  const int dstb = t << 4;

  int offA[2][4], offB[2][4];
  #pragma unroll
  for (int kk = 0; kk < 2; ++kk) {
    #pragma unroll
    for (int m = 0; m < 4; ++m) {
      const int row = wr * 64 + m * 16 + l15;
      offA[kk][m] = row * 128 + (((kk * 4 + (lane >> 4)) ^ (row & 7)) << 4);
    }
    #pragma unroll
    for (int n = 0; n < 4; ++n) {
      const int row = wc * 64 + n * 16 + l15;
      offB[kk][n] = 16384 + row * 128 + (((kk * 4 + (lane >> 4)) ^ (row & 7)) << 4);
    }
  }

  const int NT = K >> 6;
  f32x4 acc[4][4] = {};
  for (int u = 0; u < NT; ++u) {
    __syncthreads();
    const int ko = u * 64;
    #pragma unroll
    for (int i = 0; i < 4; ++i) {
      gload16(sA + (size_t)(i * 32) * K + ko, ldsb + i * 4096 + dstb);
      gload16(sB + (size_t)(i * 32) * K + ko, ldsb + 16384 + i * 4096 + dstb);
    }
    asm volatile("s_waitcnt vmcnt(0)" ::: "memory");
    __syncthreads();
    #pragma unroll
    for (int kk = 0; kk < 2; ++kk) {
      bf16x8 af[4], bfr[4];
      #pragma unroll
      for (int m = 0; m < 4; ++m) af[m] = *(const bf16x8*)(ldsb + offA[kk][m]);
      #pragma unroll
      for (int n = 0; n < 4; ++n) bfr[n] = *(const bf16x8*)(ldsb + offB[kk][n]);
      #pragma unroll
      for (int m = 0; m < 4; ++m)
        #pragma unroll
        for (int n = 0; n < 4; ++n)
          acc[m][n] = __builtin_amdgcn_mfma_f32_16x16x32_bf16(af[m], bfr[n], acc[m][n], 0, 0, 0);
    }
  }

  // epilogue: C/D layout col = lane&15, row = (lane>>4)*4 + reg  [m89-verified]
  const int ro = (lane >> 4) * 4, co = l15;
  const bool lo = (bn * 128) < NSPLIT;
  #pragma unroll
  for (int m = 0; m < 4; ++m)
    #pragma unroll
    for (int n = 0; n < 4; ++n) {
      const int gc = bn * 128 + wc * 64 + n * 16 + co;
      #pragma unroll
      for (int r = 0; r < 4; ++r) {
        const int gr = bm * 128 + wr * 64 + m * 16 + ro + r;
        float v = acc[m][n][r];
        if constexpr (ACT == 0) {
          ((float*)O1)[(size_t)gr * N + gc] = v;
        } else {
          if (lo) {
            v = v / (1.f + __expf(-v));          // silu
            ((unsigned short*)O1)[(size_t)gr * NSPLIT + gc] = f2bf(v);
          } else {
            v = 1.f / (1.f + __expf(-v));        // sigmoid
            ((unsigned short*)O2)[(size_t)gr * (N - NSPLIT) + (gc - NSPLIT)] = f2bf(v);
          }
        }
      }
    }
}

// ---------------- per-block KV outer product (MFMA), TRANSPOSED out --------
// st[(bh*NBL+j)][f][e] = sum_m (k[m][e]*kdecay[m]) * v[m][f]   (bf16)
__global__ __launch_bounds__(256) void kv_outer(
    const unsigned short* __restrict__ qkv, unsigned short* __restrict__ st) {
  const int gid = blockIdx.x;
  const int j = gid & 15;
  const int bh = gid >> 4;
  const int h = bh & 15;
  const int b = bh >> 4;
  const float slope = exp2f(-0.5f * (float)(h + 1));
  const int t = threadIdx.x;
  const int lane = t & 63, wave = t >> 6, wr = wave >> 1, wc = wave & 1;
  const int l15 = lane & 15;
  __shared__ unsigned short vt[128][72];   // vT [f][mm]
  __shared__ unsigned short kt[128][72];   // (k*kd)T [e][mm]
  f32x4 acc[4][4] = {};
  const int mm = t & 63;                   // m within chunk
  const int c0 = (t >> 6) * 32;            // 32-col span per wave
  for (int ch = 0; ch < 4; ++ch) {
    if (ch) __syncthreads();
    const int m = ch * 64 + mm;
    const int seq = b * S + j * BLK + m;
    const float kd = expf(-slope * (float)(255 - m));
    const unsigned short* row = &qkv[(size_t)seq * NQKV + h * 384];
    #pragma unroll
    for (int i = 0; i < 4; ++i) {
      const u16x8 k8 = *(const u16x8*)&row[128 + c0 + i * 8];
      const u16x8 v8 = *(const u16x8*)&row[256 + c0 + i * 8];
      #pragma unroll
      for (int q2 = 0; q2 < 8; ++q2) {
        kt[c0 + i * 8 + q2][mm] = f2bf(bf2f(k8[q2]) * kd);
        vt[c0 + i * 8 + q2][mm] = v8[q2];
      }
    }
    __syncthreads();
    #pragma unroll
    for (int kk = 0; kk < 2; ++kk) {
      bf16x8 af[4], bfr[4];
      #pragma unroll
      for (int mi = 0; mi < 4; ++mi)
        af[mi] = *(const bf16x8*)&vt[wr * 64 + mi * 16 + l15][kk * 32 + (lane >> 4) * 8];
      #pragma unroll
      for (int n = 0; n < 4; ++n)
        bfr[n] = *(const bf16x8*)&kt[wc * 64 + n * 16 + l15][kk * 32 + (lane >> 4) * 8];
      #pragma unroll
      for (int mi = 0; mi < 4; ++mi)
        #pragma unroll
        for (int n = 0; n < 4; ++n)
          acc[mi][n] = __builtin_amdgcn_mfma_f32_16x16x32_bf16(af[mi], bfr[n], acc[mi][n], 0, 0, 0);
    }
  }
  const size_t base = (size_t)gid * (D * D);
  const int ro = (lane >> 4) * 4;
  #pragma unroll
  for (int mi = 0; mi < 4; ++mi)
    #pragma unroll
    for (int n = 0; n < 4; ++n) {
      const int e = wc * 64 + n * 16 + l15;
      #pragma unroll
      for (int r = 0; r < 4; ++r) {
        const int f = wr * 64 + mi * 16 + ro + r;
        st[base + (size_t)f * D + e] = f2bf(acc[mi][n][r]);
      }
    }
}

// ---------------- exclusive decay scan over blocks (per element) -----------
__global__ __launch_bounds__(256) void kv_scan(unsigned short* __restrict__ st) {
  const int id = blockIdx.x * 256 + threadIdx.x;  // NB*H*D*D threads
  const int ef = id & (D * D - 1);
  const int bh = id >> 14;
  const int h = bh & 15;
  const float slope = exp2f(-0.5f * (float)(h + 1));
  const float bd = expf(-slope * 256.f);
  unsigned short* p = st + (size_t)bh * NBL * D * D + ef;
  float cur = 0.f;
  #pragma unroll
  for (int jj = 0; jj < NBL; ++jj) {
    const float m = bf2f(p[(size_t)jj * D * D]);
    p[(size_t)jj * D * D] = f2bf(cur);
    cur = bd * cur + m;
  }
}

// ---------------- MFMA attention (q in registers, 2 blocks/CU) -------------
// grid = ((b*H+h)*NBL + j)*2 + half ; WG = 4 waves, 128 q-rows x 128 dims.
// out = qdecay.*(q @ kvT^T) + (mask(q@k^T).*decay) @ v
__global__ __launch_bounds__(256, 2) void attn_mfma(
    const unsigned short* __restrict__ qkv, const unsigned short* __restrict__ st,
    unsigned short* __restrict__ ob) {
  const int gid = blockIdx.x;
  const int half = gid & 1;
  const int rest = gid >> 1;
  const int j = rest & 15;
  const int bh = rest >> 4;
  const int h = bh & 15;
  const int b = bh >> 4;
  const float slope = exp2f(-0.5f * (float)(h + 1));
  const int t = threadIdx.x;
  const int lane = t & 63, wave = t >> 6, wr = wave >> 1, wc = wave & 1;

  __shared__ unsigned short cb[128][136];   // kvT / k / vT chunk buffer
  __shared__ unsigned short pl[128][136];   // decayed P (m x m') bf16

  // q fragments direct from global (L2-resident; frag layout = MFMA A-frag)
  bf16x8 af[4][4];                          // [kk][m]
  #pragma unroll
  for (int m = 0; m < 4; ++m) {
    const int seq = b * S + j * BLK + half * 128 + wr * 64 + m * 16 + (lane & 15);
    const unsigned short* qrow = &qkv[(size_t)seq * NQKV + h * 384];
    #pragma unroll
    for (int kk = 0; kk < 4; ++kk)
      af[kk][m] = *(const bf16x8*)&qrow[kk * 32 + (lane >> 4) * 8];
  }
  // stage kvT (state pre-transposed [f][e], exclusive-scanned)
  {
    const int r = t >> 4, c0 = (t & 15) * 8;
    const size_t stbase = (size_t)rest * (D * D);
    #pragma unroll
    for (int p = 0; p < 8; ++p)
      *(u16x8*)&cb[r + p * 16][c0] = *(const u16x8*)&st[stbase + (size_t)(r + p * 16) * D + c0];
  }
  __syncthreads();

  f32x4 acc[4][4] = {};
  // ---- phase 1: non-diag = q @ kvT^T ----
  #pragma unroll
  for (int kk = 0; kk < 4; ++kk) {
    bf16x8 bfr[4];
    #pragma unroll
    for (int n = 0; n < 4; ++n)
      bfr[n] = *(const bf16x8*)&cb[wc * 64 + n * 16 + (lane & 15)][kk * 32 + (lane >> 4) * 8];
    #pragma unroll
    for (int m = 0; m < 4; ++m)
      #pragma unroll
      for (int n = 0; n < 4; ++n)
        acc[m][n] = __builtin_amdgcn_mfma_f32_16x16x32_bf16(af[kk][m], bfr[n], acc[m][n], 0, 0, 0);
  }
  // apply q_decay = exp(-slope*(gm+1))
  const int ro = (lane >> 4) * 4;
  #pragma unroll
  for (int m = 0; m < 4; ++m)
    #pragma unroll
    for (int r = 0; r < 4; ++r) {
      const int gm = half * 128 + wr * 64 + m * 16 + ro + r;
      const float qd = expf(-slope * (float)(gm + 1));
      #pragma unroll
      for (int n = 0; n < 4; ++n) acc[m][n][r] *= qd;
    }

  // ---- phase 2: intra-block causal, chunks of 128 k-rows ----
  const int nch = 1 + half;
  for (int c = 0; c < nch; ++c) {
    __syncthreads();                         // cb readers retired
    {
      const int r = t >> 4, c0 = (t & 15) * 8;
      #pragma unroll
      for (int p = 0; p < 8; ++p) {
        const int seq = b * S + j * BLK + c * 128 + r + p * 16;
        *(u16x8*)&cb[r + p * 16][c0] = *(const u16x8*)&qkv[(size_t)seq * NQKV + h * 384 + 128 + c0];
      }
    }
    __syncthreads();
    f32x4 sacc[4][4] = {};
    #pragma unroll
    for (int kk = 0; kk < 4; ++kk) {
      bf16x8 bfr[4];
      #pragma unroll
      for (int n = 0; n < 4; ++n)
        bfr[n] = *(const bf16x8*)&cb[wc * 64 + n * 16 + (lane & 15)][kk * 32 + (lane >> 4) * 8];
      #pragma unroll
      for (int m = 0; m < 4; ++m)
        #pragma unroll
        for (int n = 0; n < 4; ++n)
          sacc[m][n] = __builtin_amdgcn_mfma_f32_16x16x32_bf16(af[kk][m], bfr[n], sacc[m][n], 0, 0, 0);
    }
    // decay+mask -> P (bf16) in LDS
    #pragma unroll
    for (int m = 0; m < 4; ++m)
      #pragma unroll
      for (int n = 0; n < 4; ++n) {
        const int lc = wc * 64 + n * 16 + (lane & 15);
        const int gp = c * 128 + lc;
        #pragma unroll
        for (int r = 0; r < 4; ++r) {
          const int lm = wr * 64 + m * 16 + ro + r;
          const int gm = half * 128 + lm;
          const float dd = (gm >= gp) ? expf(-slope * (float)(gm - gp)) : 0.f;
          pl[lm][lc] = f2bf(sacc[m][n][r] * dd);
        }
      }
    __syncthreads();                         // P complete; cb(k) readers done
    // stage v transposed: cb[f][m']
    {
      const int vr = t & 15, vc0 = (t >> 4) * 8;
      #pragma unroll
      for (int p = 0; p < 8; ++p) {
        const int row = vr + p * 16;
        const int seq = b * S + j * BLK + c * 128 + row;
        const u16x8 vv = *(const u16x8*)&qkv[(size_t)seq * NQKV + h * 384 + 256 + vc0];
        #pragma unroll
        for (int i = 0; i < 8; ++i) cb[vc0 + i][row] = vv[i];
      }
    }
    __syncthreads();
    // PV: acc += P @ vT^T
    #pragma unroll
    for (int kk = 0; kk < 4; ++kk) {
      bf16x8 pf[4], bfr[4];
      #pragma unroll
      for (int m = 0; m < 4; ++m)
        pf[m] = *(const bf16x8*)&pl[wr * 64 + m * 16 + (lane & 15)][kk * 32 + (lane >> 4) * 8];
      #pragma unroll
      for (int n = 0; n < 4; ++n)
        bfr[n] = *(const bf16x8*)&cb[wc * 64 + n * 16 + (lane & 15)][kk * 32 + (lane >> 4) * 8];
      #pragma unroll
      for (int m = 0; m < 4; ++m)
        #pragma unroll
        for (int n = 0; n < 4; ++n)
          acc[m][n] = __builtin_amdgcn_mfma_f32_16x16x32_bf16(pf[m], bfr[n], acc[m][n], 0, 0, 0);
    }
  }

  // epilogue: ob[b][n][h*D + f]
  #pragma unroll
  for (int m = 0; m < 4; ++m)
    #pragma unroll
    for (int n = 0; n < 4; ++n) {
      const int fc = h * D + wc * 64 + n * 16 + (lane & 15);
      #pragma unroll
      for (int r = 0; r < 4; ++r) {
        const int seq = b * S + j * BLK + half * 128 + wr * 64 + m * 16 + ro + r;
        ob[(size_t)seq * HD + fc] = f2bf(acc[m][n][r]);
      }
    }
}

// ---------------- RMSNorm * norm_w * sigmoid-gate -> bf16 ------------------
__global__ __launch_bounds__(256) void norm_gate(
    const unsigned short* __restrict__ ob, const unsigned short* __restrict__ gb,
    const float* __restrict__ nw, unsigned short* __restrict__ og) {
  const int row = blockIdx.x;
  const int t = threadIdx.x;
  const u16x8 ov = *(const u16x8*)&ob[(size_t)row * HD + t * 8];
  float f[8];
  float ss = 0.f;
  #pragma unroll
  for (int i = 0; i < 8; ++i) { f[i] = bf2f(ov[i]); ss += f[i] * f[i]; }
  #pragma unroll
  for (int off = 32; off > 0; off >>= 1) ss += __shfl_down(ss, off, 64);
  __shared__ float red[4];
  if ((t & 63) == 0) red[t >> 6] = ss;
  __syncthreads();
  const float rms = rsqrtf((red[0] + red[1] + red[2] + red[3]) * (1.f / HD) + 1e-6f);
  const u16x8 gv = *(const u16x8*)&gb[(size_t)row * HD + t * 8];
  u16x8 ow;
  #pragma unroll
  for (int i = 0; i < 8; ++i)
    ow[i] = f2bf(f[i] * rms * nw[t * 8 + i] * bf2f(gv[i]));
  *(u16x8*)&og[(size_t)row * HD + t * 8] = ow;
}

extern "C" void kernel_launch(void* const* d_in, const int* in_sizes, int n_in,
                              void* d_out, int out_size, void* d_ws, size_t ws_size,
                              hipStream_t stream) {
  (void)in_sizes; (void)n_in; (void)out_size; (void)ws_size;
  const float* x    = (const float*)d_in[0];
  const float* Wqkv = (const float*)d_in[1];
  const float* Wg   = (const float*)d_in[2];
  const float* Wout = (const float*)d_in[3];
  const float* nw   = (const float*)d_in[4];

  char* ws = (char*)d_ws;
  unsigned short* xb    = (unsigned short*)ws; ws += SZ_XB;
  unsigned short* wqkvt = (unsigned short*)ws; ws += SZ_WQKVT;  // [6144][2048]
  unsigned short* wgt   = (unsigned short*)ws; ws += SZ_WGT;    // [2048][2048] (contiguous after wqkvt)
  unsigned short* woutt = (unsigned short*)ws; ws += SZ_WOUTT;
  unsigned short* qkvb  = (unsigned short*)ws; ws += SZ_QKVB;
  unsigned short* gb    = (unsigned short*)ws; ws += SZ_GB;
  unsigned short* st    = (unsigned short*)ws; ws += SZ_ST;
  unsigned short* ob    = (unsigned short*)ws; ws += SZ_OB;
  unsigned short* og    = xb;  // alias: xb dead after the fused GEMM
  (void)wgt;

  cvt_bf16<<<dim3((NB * S * DIN) / (256 * 8)), 256, 0, stream>>>(x, xb);
  transpose_cvt<<<dim3(NQKV / 32, DIN / 32), 256, 0, stream>>>(Wqkv, wqkvt, DIN, NQKV);
  transpose_cvt<<<dim3(HD / 32, DIN / 32), 256, 0, stream>>>(Wg, wgt, DIN, HD);
  transpose_cvt<<<dim3(HD / 32, HD / 32), 256, 0, stream>>>(Wout, woutt, HD, HD);

  // fused: [qkv | gate] = x @ [Wqkv | Wg]; N = 8192, split at 6144
  gemm128<3><<<dim3((NB * S / 128) * ((NQKV + HD) / 128)), 256, 0, stream>>>(
      xb, wqkvt, qkvb, gb, NB * S, NQKV + HD, DIN, NQKV);

  kv_outer<<<dim3(NB * H * NBL), 256, 0, stream>>>(qkvb, st);
  kv_scan<<<dim3((NB * H * D * D) / 256), 256, 0, stream>>>(st);
  attn_mfma<<<dim3(NB * H * NBL * 2), 256, 0, stream>>>(qkvb, st, ob);

  norm_gate<<<dim3(NB * S), 256, 0, stream>>>(ob, gb, nw, og);
  gemm128<0><<<dim3((NB * S / 128) * (HD / 128)), 256, 0, stream>>>(
      og, woutt, d_out, nullptr, NB * S, HD, HD, 0);
}